// Round 12
// baseline (195.243 us; speedup 1.0000x reference)
//
#include <hip/hip_runtime.h>

// LIF net on MI355X.  R12: occupancy-first GEMM (small acc -> 24+ waves/CU).
//  1. convert_W: Bt[13][256][64] bf16 linear (relu, K-pad 832) + wrelu f32
//  2. gemm_hidden: grid 2048 = (b, t-eighth, n-half); tile 64m x 128n, BK=64;
//     acc 2x2 frags (16 AGPR); A slot-swizzled LDS dbuf (2x8KB), 1-ahead reg
//     prefetch; B frags direct from L2 Bt; lgkm-only barriers.
//     Epilogue transpose -> Ih[b][h][512] bf16.
//  3. scan_h: wave-per-row parallel LIF scan (shfl_up affine composition)
//  4. out_fused: per-b VALU dot (K=256,N=10) -> LDS -> segmented v_o scan
// ws: wrelu @0 (10KB) | Bt @16KB (416KB) | Ih @512KB (33.55MB)

typedef __attribute__((ext_vector_type(4))) float  floatx4;
typedef __attribute__((ext_vector_type(8))) short  shortx8;
typedef unsigned short u16;
typedef unsigned int   u32;

#define B_   128
#define NIN  784
#define NH   256
#define NO   10
#define T_   500
#define NK   13            // K padded to 832, tiles of 64

__device__ __forceinline__ u16 f2bf(float f) {
    union { float f; u32 u; } x; x.f = f;
    u32 r = x.u + 0x7FFFu + ((x.u >> 16) & 1u);   // RNE
    return (u16)(r >> 16);
}
__device__ __forceinline__ float bf2f(u16 u) {
    union { u32 u; float f; } x; x.u = ((u32)u) << 16; return x.f;
}
__device__ __forceinline__ float sigmoid5(float v) {
    return 1.0f / (1.0f + __expf(-5.0f * (v - 1.0f)));
}

// LDS-only barrier: ds ops drained, vmem loads stay in flight
#define BARRIER { asm volatile("s_waitcnt lgkmcnt(0)" ::: "memory");           \
                  __builtin_amdgcn_s_barrier(); }

// ---------- Pre-pass: Bt[kt][n][kk] bf16 linear (relu, padded) + wrelu ----------
__global__ void convert_W(const float* __restrict__ w_ih,
                          const float* __restrict__ w_ho,
                          u16* __restrict__ Bt, float* __restrict__ wrelu) {
    if (blockIdx.x == NK * 64) {
        for (int i = threadIdx.x; i < NH * NO; i += 256)
            wrelu[i] = fmaxf(0.f, w_ho[i]);
        return;
    }
    const int k = blockIdx.x;           // 0..831
    const int n = threadIdx.x;          // 0..255
    const float f = (k < NIN) ? fmaxf(0.f, w_ih[k * NH + n]) : 0.f;
    Bt[(size_t)(k >> 6) * 16384 + n * 64 + (k & 63)] = f2bf(f);
}

// ---------- hidden GEMM ----------
// 2048 blocks = (b, tq 0..7, nh 0..1); 512 thr = 8 waves (2 wm x 4 wn),
// wave tile 32m x 32n (2x2 frags, 16 acc).  LDS 16KB: As dbuf 2x8KB
// ([64 m][64 k] slot-swizzled); epilogue Cs[128][64] aliases.
__global__ __launch_bounds__(512, 6) void gemm_hidden(
    const float* __restrict__ spikes,   // [128][784][500] f32
    const u16* __restrict__ Bt,         // [13][256][64] bf16 linear
    u16* __restrict__ Ih)               // [128][256][512] bf16
{
    __shared__ u16 SH[8192];            // 16KB
    u16* AS0 = SH;                      // 4096 u16 = 8KB
    u16* AS1 = SH + 4096;

    const int tid = threadIdx.x;
    const int nh  = blockIdx.x & 1;
    const int tq  = (blockIdx.x >> 1) & 7;
    const int b   = blockIdx.x >> 4;
    const int t0  = tq * 64;

    // A staging: thread = (kp 0..31 -> k=2kp,2kp+1; tg 0..15 -> t=t0+4tg)
    const int kp = tid >> 4, tg = tid & 15;
    const int tloc = t0 + tg * 4;
    const int oct  = kp >> 2;           // k-octet 0..7
    const int koff = (2 * kp) & 7;
    const bool t_ok = (tloc <= 496);
    const float* sbase = spikes + (size_t)b * (NIN * T_) + tloc;

    // MFMA roles
    const int lane = tid & 63, wid = tid >> 6;
    const int wm = wid >> 2, wn = wid & 3;             // wm 0..1, wn 0..3
    const int lg = lane >> 4, lr = lane & 15;
    int aBase[2], ax[2], bOff[2];
#pragma unroll
    for (int mi = 0; mi < 2; ++mi) {
        const int m = wm * 32 + mi * 16 + lr;
        aBase[mi] = m * 64;  ax[mi] = m & 7;
    }
#pragma unroll
    for (int ni = 0; ni < 2; ++ni) {
        const int n_g = nh * 128 + wn * 32 + ni * 16 + lr;
        bOff[ni] = n_g * 64;            // + ks*32 + lg*8 at use
    }

    floatx4 acc[2][2];
#pragma unroll
    for (int i = 0; i < 2; ++i)
#pragma unroll
        for (int j = 0; j < 2; ++j) acc[i][j] = (floatx4)0.f;

#define LOADA(v0, v1, itv) {                                                   \
        const int gk = (itv) * 64 + 2 * kp;                                    \
        const bool ok0 = t_ok && (gk < NIN);                                   \
        const bool ok1 = t_ok && (gk + 1 < NIN);                               \
        const float* p0 = ok0 ? (sbase + (size_t)gk * T_) : sbase;             \
        const float* p1 = ok1 ? (sbase + (size_t)(gk + 1) * T_) : sbase;       \
        floatx4 u0 = *(const floatx4*)p0;                                      \
        floatx4 u1 = *(const floatx4*)p1;                                      \
        v0 = ok0 ? u0 : (floatx4)0.f;                                          \
        v1 = ok1 ? u1 : (floatx4)0.f; }

#define WRITEA(ASX, v0, v1) { _Pragma("unroll") for (int j = 0; j < 4; ++j) {  \
        const int m = tg * 4 + j;                                              \
        const int slot = oct ^ (m & 7);                                        \
        const u32 pk = (u32)f2bf(v0[j]) | ((u32)f2bf(v1[j]) << 16);            \
        *(u32*)&(ASX)[m * 64 + slot * 8 + koff] = pk; } }

#define MFMAIT(ASX, itv) { const u16* bsrc = Bt + (size_t)(itv) * 16384;       \
        _Pragma("unroll") for (int ks = 0; ks < 2; ++ks) {                     \
            shortx8 af[2], bf[2];                                              \
            _Pragma("unroll") for (int mi = 0; mi < 2; ++mi)                   \
                af[mi] = *(const shortx8*)&(ASX)[aBase[mi] +                   \
                            (((ks * 4 + lg) ^ ax[mi]) << 3)];                  \
            _Pragma("unroll") for (int ni = 0; ni < 2; ++ni)                   \
                bf[ni] = *(const shortx8*)(bsrc + bOff[ni] + ks * 32 + lg * 8);\
            _Pragma("unroll") for (int mi = 0; mi < 2; ++mi)                   \
            _Pragma("unroll") for (int ni = 0; ni < 2; ++ni)                   \
                acc[mi][ni] = __builtin_amdgcn_mfma_f32_16x16x32_bf16(         \
                    af[mi], bf[ni], acc[mi][ni], 0, 0, 0); } }

    floatx4 vaP0, vaP1, vaQ0, vaQ1;

    // prologue
    LOADA(vaP0, vaP1, 0);
    WRITEA(AS0, vaP0, vaP1);            // counted vmcnt for vaP only
    LOADA(vaQ0, vaQ1, 1);
    BARRIER;

    // body: 12 = 2x6 iters, tail iter 12
    for (int it = 0; it < 12; it += 2) {
        WRITEA(AS1, vaQ0, vaQ1);        // tile it+1
        LOADA(vaP0, vaP1, it + 2);
        MFMAIT(AS0, it);
        BARRIER;
        WRITEA(AS0, vaP0, vaP1);        // tile it+2
        if (it + 3 < NK) LOADA(vaQ0, vaQ1, it + 3);
        MFMAIT(AS1, it + 1);
        BARRIER;
    }
    MFMAIT(AS0, 12);                    // tile 12
    BARRIER;                            // LDS reads done; SH free for Cs

    // ---- epilogue: Cs[128 n_l][64 m] (16KB) -> Ih[b][nh*128+n][t0+m] ----
    u16* Cs = SH;
#pragma unroll
    for (int mi = 0; mi < 2; ++mi)
#pragma unroll
        for (int rr = 0; rr < 2; ++rr) {
            const int m0 = wm * 32 + mi * 16 + lg * 4 + rr * 2;
#pragma unroll
            for (int ni = 0; ni < 2; ++ni) {
                const int n_l = wn * 32 + ni * 16 + lr;
                const u32 pk = (u32)f2bf(acc[mi][ni][rr * 2]) |
                               ((u32)f2bf(acc[mi][ni][rr * 2 + 1]) << 16);
                *(u32*)&Cs[n_l * 64 + (m0 ^ ((n_l & 7) << 3))] = pk;
            }
        }
    BARRIER;
    {
        const int n_l = tid >> 2, ms = tid & 3;
        u16* gdst = Ih + ((size_t)b * 256 + nh * 128 + n_l) * 512 + t0 + ms * 16;
#pragma unroll
        for (int j = 0; j < 2; ++j) {
            const uint4 v = *(const uint4*)&Cs[n_l * 64 +
                            ((ms * 16 + j * 8) ^ ((n_l & 7) << 3))];
            *(uint4*)(gdst + j * 8) = v;
        }
    }
#undef LOADA
#undef WRITEA
#undef MFMAIT
}

// ---------- parallel hidden LIF scan (in place) ----------
__global__ __launch_bounds__(512) void scan_h(u16* __restrict__ Ih) {
    const int lane = threadIdx.x & 63;
    const int row  = blockIdx.x * 8 + (threadIdx.x >> 6);
    u16* p = Ih + (size_t)row * 512 + lane * 8;
    shortx8 xv = *(const shortx8*)p;
    float I[8];
#pragma unroll
    for (int j = 0; j < 8; ++j) I[j] = bf2f((u16)xv[j]);
    float z = 0.f;
#pragma unroll
    for (int j = 0; j < 8; ++j) z += (I[j] - z) * 0.1f;
    float A = 0.43046721f, Bv = z;                 // 0.9^8
#pragma unroll
    for (int d = 1; d < 64; d <<= 1) {
        const float Au = __shfl_up(A, d);
        const float Bu = __shfl_up(Bv, d);
        if (lane >= d) { Bv = fmaf(A, Bu, Bv); A *= Au; }
    }
    float v = __shfl_up(Bv, 1);
    if (lane == 0) v = 0.f;
#pragma unroll
    for (int j = 0; j < 8; ++j) {
        v += (I[j] - v) * 0.1f;
        xv[j] = (short)f2bf(sigmoid5(v));
    }
    *(shortx8*)p = xv;
}

// ---------- output dot + segmented v_o scan ----------
__global__ __launch_bounds__(512) void out_fused(
    const u16* __restrict__ s,          // [128][256][512] bf16
    const float* __restrict__ wr,       // [256][10] relu'd f32
    float* __restrict__ out)
{
    __shared__ float Io[T_ * NO];
    __shared__ float vend[25][NO], vstart[25][NO], psum[25][NO];
    const int b = blockIdx.x, tid = threadIdx.x;

    float acc[NO];
#pragma unroll
    for (int o = 0; o < NO; ++o) acc[o] = 0.f;
    const u16* sb = s + (size_t)b * NH * 512 + tid;
#pragma unroll 2
    for (int h = 0; h < NH; ++h) {
        const float sv = bf2f(sb[h * 512]);
#pragma unroll
        for (int o = 0; o < NO; ++o) acc[o] = fmaf(sv, wr[h * NO + o], acc[o]);
    }
    if (tid < T_) {
#pragma unroll
        for (int o = 0; o < NO; ++o) Io[tid * NO + o] = acc[o];
    }
    __syncthreads();

    const int seg = tid / NO, o = tid - seg * NO;
    if (tid < 250) {
        float v = 0.f;
#pragma unroll
        for (int j = 0; j < 20; ++j)
            v += (Io[(seg * 20 + j) * NO + o] - v) * 0.1f;
        vend[seg][o] = v;
    }
    __syncthreads();
    if (tid < NO) {
        float vs = 0.f;
#pragma unroll
        for (int sg = 0; sg < 25; ++sg) {
            vstart[sg][tid] = vs;
            vs = vend[sg][tid] + 0.12157665459f * vs;   // 0.9^20
        }
    }
    __syncthreads();
    if (tid < 250) {
        float v = vstart[seg][o], ps = 0.f;
#pragma unroll
        for (int j = 0; j < 20; ++j) {
            const int t = seg * 20 + j;
            v += (Io[t * NO + o] - v) * 0.1f;
            const float sv = sigmoid5(v);
            out[(size_t)b * (NO * T_) + (size_t)o * T_ + t] = sv;
            ps += sv;
        }
        psum[seg][o] = ps;
    }
    __syncthreads();
    if (tid < NO) {
        float tot = 0.f;
#pragma unroll
        for (int sg = 0; sg < 25; ++sg) tot += psum[sg][tid];
        out[(size_t)(B_ * NO) * T_ + b * NO + tid] = tot * (1.0f / T_);
    }
}

extern "C" void kernel_launch(void* const* d_in, const int* in_sizes, int n_in,
                              void* d_out, int out_size, void* d_ws, size_t ws_size,
                              hipStream_t stream) {
    (void)in_sizes; (void)n_in; (void)out_size; (void)ws_size;
    const float* spikes = (const float*)d_in[0];   // [128][784][500]
    const float* w_ih   = (const float*)d_in[1];   // [784][256]
    const float* w_ho   = (const float*)d_in[2];   // [256][10]
    float* out = (float*)d_out;

    float* wrelu = (float*)d_ws;                            // 10KB @0
    u16*   Bt    = (u16*)((char*)d_ws + 16384);             // 416KB
    u16*   Ih    = (u16*)((char*)d_ws + 524288);            // 33.55MB

    convert_W  <<<NK * 64 + 1, 256, 0, stream>>>(w_ih, w_ho, Bt, wrelu);
    gemm_hidden<<<2048, 512, 0, stream>>>(spikes, Bt, Ih);
    scan_h     <<<4096, 512, 0, stream>>>(Ih);
    out_fused  <<<B_, 512, 0, stream>>>(Ih, wrelu, out);
}

// Round 13
// 140.731 us; speedup vs baseline: 1.3873x; 1.3873x over previous
//
#include <hip/hip_runtime.h>

// LIF net on MI355X.  R13 = R11 with 1KB A-runs (m-tile = 256 t):
//  1. convert_W: Bt[25][256][32] bf16 linear (relu, K-pad 800) + wrelu f32
//  2. gemm_hidden: grid 512 = (b, t-half, n-half); tile 256m x 128n, BK=32;
//     each wave-load = one 1KB contiguous t-run; A slot-swizzled LDS dbuf
//     (2x16KB); B single-buffered regs from L2 Bt; lgkm-only barriers.
//     Epilogue (4 wm rounds) -> Ih[b][h][512] bf16.
//  3. scan_h: wave-per-row parallel LIF scan (shfl_up affine composition)
//  4. out_fused: per-b VALU dot (K=256,N=10) -> LDS -> segmented v_o scan
// ws: wrelu @0 (10KB) | Bt @16KB (400KB) | Ih @512KB (33.55MB)

typedef __attribute__((ext_vector_type(4))) float  floatx4;
typedef __attribute__((ext_vector_type(8))) short  shortx8;
typedef unsigned short u16;
typedef unsigned int   u32;

#define B_   128
#define NIN  784
#define NH   256
#define NO   10
#define T_   500
#define NK   25            // K padded to 800, tiles of 32

__device__ __forceinline__ u16 f2bf(float f) {
    union { float f; u32 u; } x; x.f = f;
    u32 r = x.u + 0x7FFFu + ((x.u >> 16) & 1u);   // RNE
    return (u16)(r >> 16);
}
__device__ __forceinline__ float bf2f(u16 u) {
    union { u32 u; float f; } x; x.u = ((u32)u) << 16; return x.f;
}
__device__ __forceinline__ float sigmoid5(float v) {
    return 1.0f / (1.0f + __expf(-5.0f * (v - 1.0f)));
}

// LDS-only barrier: ds ops drained, vmem loads stay in flight
#define BARRIER { asm volatile("s_waitcnt lgkmcnt(0)" ::: "memory");           \
                  __builtin_amdgcn_s_barrier(); }

// ---------- Pre-pass: Bt[kt][n][kk] bf16 linear (relu, padded) + wrelu ----------
__global__ void convert_W(const float* __restrict__ w_ih,
                          const float* __restrict__ w_ho,
                          u16* __restrict__ Bt, float* __restrict__ wrelu) {
    if (blockIdx.x == NK * 32) {
        for (int i = threadIdx.x; i < NH * NO; i += 256)
            wrelu[i] = fmaxf(0.f, w_ho[i]);
        return;
    }
    const int k = blockIdx.x;           // 0..799
    const int n = threadIdx.x;          // 0..255
    const float f = (k < NIN) ? fmaxf(0.f, w_ih[k * NH + n]) : 0.f;
    Bt[(size_t)(k >> 5) * 8192 + n * 32 + (k & 31)] = f2bf(f);
}

// ---------- hidden GEMM ----------
// 512 blocks = (b, th, nh); 512 thr = 8 waves (4 wm x 2 wn), wave tile
// 64m x 64n (4x4 frags, 64 AGPR).  LDS 32KB: As dbuf 2x16KB
// ([256 m][32 k] slot-swizzled); epilogue Cs[128][64] (16KB) aliases AS0.
__global__ __launch_bounds__(512, 4) void gemm_hidden(
    const float* __restrict__ spikes,   // [128][784][500] f32
    const u16* __restrict__ Bt,         // [25][256][32] bf16 linear
    u16* __restrict__ Ih)               // [128][256][512] bf16
{
    __shared__ u16 SH[16384];           // 32KB
    u16* AS0 = SH;                      // 8192 u16 = 16KB
    u16* AS1 = SH + 8192;

    const int tid = threadIdx.x;
    const int nh  = blockIdx.x & 1;
    const int th  = (blockIdx.x >> 1) & 1;
    const int b   = blockIdx.x >> 2;
    const int t0  = th * 256;
    const int n0  = nh * 128;

    // A staging: thread = (kq 0..7 -> k=4kq..4kq+3; tg 0..63 -> t=t0+4tg)
    // One wave-load = one 1KB contiguous run of a k-row.
    const int kq = tid >> 6, tg = tid & 63;
    const int tloc = t0 + tg * 4;
    const bool t_ok = (tloc <= 496);
    const float* sbase = spikes + (size_t)b * (NIN * T_) + tloc;
    const int oct  = kq >> 1;                    // k-octet 0..3
    const int koff = (4 * kq) & 7;               // 0 or 4

    // MFMA roles
    const int lane = tid & 63, wid = tid >> 6;
    const int wm = wid >> 1, wn = wid & 1;       // wm 0..3, wn 0..1
    const int lg = lane >> 4, lr = lane & 15;
    int aBase[4], ax3[4], bOff[4];
#pragma unroll
    for (int mi = 0; mi < 4; ++mi) {
        const int m = wm * 64 + mi * 16 + lr;
        aBase[mi] = m * 32;
        ax3[mi] = (m & 3) ^ ((m >> 2) & 3);
    }
#pragma unroll
    for (int ni = 0; ni < 4; ++ni)
        bOff[ni] = (n0 + wn * 64 + ni * 16 + lr) * 32 + lg * 8;

    floatx4 acc[4][4];
#pragma unroll
    for (int i = 0; i < 4; ++i)
#pragma unroll
        for (int j = 0; j < 4; ++j) acc[i][j] = (floatx4)0.f;

#define LOADA(va, itv) { const int gk0 = (itv) * 32 + 4 * kq;                  \
        _Pragma("unroll") for (int r = 0; r < 4; ++r) {                        \
            const bool ok = t_ok && (gk0 + r < NIN);                           \
            const float* p = ok ? (sbase + (size_t)(gk0 + r) * T_) : sbase;    \
            floatx4 u = *(const floatx4*)p;                                    \
            va[r] = ok ? u : (floatx4)0.f; } }

#define WRITEA(ASX, va) { _Pragma("unroll") for (int j = 0; j < 4; ++j) {      \
        const int m = tg * 4 + j;                                              \
        const int slot = oct ^ (m & 3) ^ ((m >> 2) & 3);                       \
        const u32 p0 = (u32)f2bf(va[0][j]) | ((u32)f2bf(va[1][j]) << 16);      \
        const u32 p1 = (u32)f2bf(va[2][j]) | ((u32)f2bf(va[3][j]) << 16);      \
        *(u32*)&(ASX)[m * 32 + slot * 8 + koff]     = p0;                      \
        *(u32*)&(ASX)[m * 32 + slot * 8 + koff + 2] = p1; } }

#define LOADB(bfv, itv) { const u16* src = Bt + (size_t)(itv) * 8192;          \
        _Pragma("unroll") for (int ni = 0; ni < 4; ++ni)                       \
            bfv[ni] = *(const shortx8*)(src + bOff[ni]); }

#define MFMAIT(ASX, bfv) { shortx8 af[4];                                      \
        _Pragma("unroll") for (int mi = 0; mi < 4; ++mi)                       \
            af[mi] = *(const shortx8*)&(ASX)[aBase[mi] +                       \
                        (((lg ^ ax3[mi])) << 3)];                              \
        _Pragma("unroll") for (int mi = 0; mi < 4; ++mi)                       \
        _Pragma("unroll") for (int ni = 0; ni < 4; ++ni)                       \
            acc[mi][ni] = __builtin_amdgcn_mfma_f32_16x16x32_bf16(             \
                af[mi], bfv[ni], acc[mi][ni], 0, 0, 0); }

    floatx4 vaP[4];
    shortx8 bf[4];

    // prologue: tile0 staged, tile1 A in flight
    LOADA(vaP, 0);
    WRITEA(AS0, vaP);                   // counted vmcnt waits vaP only
    LOADA(vaP, 1);
    BARRIER;

    // body: iter it computes tile it, stages tile it+1, prefetches A(it+2)
    for (int it = 0; it < 24; it += 2) {
        LOADB(bf, it);
        WRITEA(AS1, vaP);
        LOADA(vaP, it + 2);
        MFMAIT(AS0, bf);
        BARRIER;
        LOADB(bf, it + 1);
        WRITEA(AS0, vaP);
        if (it + 3 < NK) LOADA(vaP, it + 3);
        MFMAIT(AS1, bf);
        BARRIER;
    }
    LOADB(bf, 24);
    MFMAIT(AS0, bf);                    // tile 24
    BARRIER;                            // LDS reads done; SH free for Cs

    // ---- epilogue: 4 wm-rounds via Cs[128 n_l][64 m] (16KB, aliases AS0) ----
    u16* Cs = SH;
#pragma unroll
    for (int h = 0; h < 4; ++h) {
        if (wm == h) {
#pragma unroll
            for (int mi = 0; mi < 4; ++mi)
#pragma unroll
                for (int rr = 0; rr < 2; ++rr) {
                    const int mloc = mi * 16 + lg * 4 + rr * 2;
#pragma unroll
                    for (int ni = 0; ni < 4; ++ni) {
                        const int n_l = wn * 64 + ni * 16 + lr;
                        const u32 pk = (u32)f2bf(acc[mi][ni][rr * 2]) |
                                       ((u32)f2bf(acc[mi][ni][rr * 2 + 1]) << 16);
                        *(u32*)&Cs[n_l * 64 + (mloc ^ ((n_l & 7) << 3))] = pk;
                    }
                }
        }
        BARRIER;
        {
            const int n_l = tid >> 2, ms = tid & 3;
            u16* gdst = Ih + ((size_t)b * 256 + n0 + n_l) * 512 + t0 + h * 64 + ms * 16;
#pragma unroll
            for (int j = 0; j < 2; ++j) {
                const uint4 v = *(const uint4*)&Cs[n_l * 64 +
                                ((ms * 16 + j * 8) ^ ((n_l & 7) << 3))];
                *(uint4*)(gdst + j * 8) = v;
            }
        }
        BARRIER;
    }
#undef LOADA
#undef WRITEA
#undef LOADB
#undef MFMAIT
}

// ---------- parallel hidden LIF scan (in place) ----------
__global__ __launch_bounds__(512) void scan_h(u16* __restrict__ Ih) {
    const int lane = threadIdx.x & 63;
    const int row  = blockIdx.x * 8 + (threadIdx.x >> 6);
    u16* p = Ih + (size_t)row * 512 + lane * 8;
    shortx8 xv = *(const shortx8*)p;
    float I[8];
#pragma unroll
    for (int j = 0; j < 8; ++j) I[j] = bf2f((u16)xv[j]);
    float z = 0.f;
#pragma unroll
    for (int j = 0; j < 8; ++j) z += (I[j] - z) * 0.1f;
    float A = 0.43046721f, Bv = z;                 // 0.9^8
#pragma unroll
    for (int d = 1; d < 64; d <<= 1) {
        const float Au = __shfl_up(A, d);
        const float Bu = __shfl_up(Bv, d);
        if (lane >= d) { Bv = fmaf(A, Bu, Bv); A *= Au; }
    }
    float v = __shfl_up(Bv, 1);
    if (lane == 0) v = 0.f;
#pragma unroll
    for (int j = 0; j < 8; ++j) {
        v += (I[j] - v) * 0.1f;
        xv[j] = (short)f2bf(sigmoid5(v));
    }
    *(shortx8*)p = xv;
}

// ---------- output dot + segmented v_o scan ----------
__global__ __launch_bounds__(512) void out_fused(
    const u16* __restrict__ s,          // [128][256][512] bf16
    const float* __restrict__ wr,       // [256][10] relu'd f32
    float* __restrict__ out)
{
    __shared__ float Io[T_ * NO];
    __shared__ float vend[25][NO], vstart[25][NO], psum[25][NO];
    const int b = blockIdx.x, tid = threadIdx.x;

    float acc[NO];
#pragma unroll
    for (int o = 0; o < NO; ++o) acc[o] = 0.f;
    const u16* sb = s + (size_t)b * NH * 512 + tid;
#pragma unroll 2
    for (int h = 0; h < NH; ++h) {
        const float sv = bf2f(sb[h * 512]);
#pragma unroll
        for (int o = 0; o < NO; ++o) acc[o] = fmaf(sv, wr[h * NO + o], acc[o]);
    }
    if (tid < T_) {
#pragma unroll
        for (int o = 0; o < NO; ++o) Io[tid * NO + o] = acc[o];
    }
    __syncthreads();

    const int seg = tid / NO, o = tid - seg * NO;
    if (tid < 250) {
        float v = 0.f;
#pragma unroll
        for (int j = 0; j < 20; ++j)
            v += (Io[(seg * 20 + j) * NO + o] - v) * 0.1f;
        vend[seg][o] = v;
    }
    __syncthreads();
    if (tid < NO) {
        float vs = 0.f;
#pragma unroll
        for (int sg = 0; sg < 25; ++sg) {
            vstart[sg][tid] = vs;
            vs = vend[sg][tid] + 0.12157665459f * vs;   // 0.9^20
        }
    }
    __syncthreads();
    if (tid < 250) {
        float v = vstart[seg][o], ps = 0.f;
#pragma unroll
        for (int j = 0; j < 20; ++j) {
            const int t = seg * 20 + j;
            v += (Io[t * NO + o] - v) * 0.1f;
            const float sv = sigmoid5(v);
            out[(size_t)b * (NO * T_) + (size_t)o * T_ + t] = sv;
            ps += sv;
        }
        psum[seg][o] = ps;
    }
    __syncthreads();
    if (tid < NO) {
        float tot = 0.f;
#pragma unroll
        for (int sg = 0; sg < 25; ++sg) tot += psum[sg][tid];
        out[(size_t)(B_ * NO) * T_ + b * NO + tid] = tot * (1.0f / T_);
    }
}

extern "C" void kernel_launch(void* const* d_in, const int* in_sizes, int n_in,
                              void* d_out, int out_size, void* d_ws, size_t ws_size,
                              hipStream_t stream) {
    (void)in_sizes; (void)n_in; (void)out_size; (void)ws_size;
    const float* spikes = (const float*)d_in[0];   // [128][784][500]
    const float* w_ih   = (const float*)d_in[1];   // [784][256]
    const float* w_ho   = (const float*)d_in[2];   // [256][10]
    float* out = (float*)d_out;

    float* wrelu = (float*)d_ws;                            // 10KB @0
    u16*   Bt    = (u16*)((char*)d_ws + 16384);             // 400KB
    u16*   Ih    = (u16*)((char*)d_ws + 524288);            // 33.55MB

    convert_W  <<<NK * 32 + 1, 256, 0, stream>>>(w_ih, w_ho, Bt, wrelu);
    gemm_hidden<<<512, 512, 0, stream>>>(spikes, Bt, Ih);
    scan_h     <<<4096, 512, 0, stream>>>(Ih);
    out_fused  <<<B_, 512, 0, stream>>>(Ih, wrelu, out);
}

// Round 14
// 100.018 us; speedup vs baseline: 1.9521x; 1.4071x over previous
//
#include <hip/hip_runtime.h>

// LIF net on MI355X.  R14 = R9 gemm (best measured) + split high-occupancy tail.
//  1. convert_W: Bt[25][256][32] bf16 (relu, slot-swizzled, K-pad 800) + wrelu
//  2. gemm_hidden (R9 verbatim): 512 blocks (b, tq), tile 128m x 256n, BK=32,
//     48KB LDS dbuf, A reg-prefetch, B gload16 -> Ih[b][h][512] bf16
//  3. scan_h: wave-per-row parallel LIF scan (shfl_up affine composition)
//  4. gemm_out: 512 blocks (b, tq) x 512 thr (t-local x h-quarter), LDS
//     reduce -> Io[b][t][o] f32
//  5. lif_out: per-b segmented v_o scan from Io -> outputs
// ws: wrelu @0 (10KB) | Bt @16KB (400KB) | Ih @512KB (33.55MB) | Io @34MB (2.56MB)

typedef __attribute__((ext_vector_type(4))) float  floatx4;
typedef __attribute__((ext_vector_type(8))) short  shortx8;
typedef unsigned short u16;
typedef unsigned int   u32;

#define B_   128
#define NIN  784
#define NH   256
#define NO   10
#define T_   500
#define NK   25            // K padded to 800, tiles of 32

__device__ __forceinline__ u16 f2bf(float f) {
    union { float f; u32 u; } x; x.f = f;
    u32 r = x.u + 0x7FFFu + ((x.u >> 16) & 1u);   // RNE
    return (u16)(r >> 16);
}
__device__ __forceinline__ float bf2f(u16 u) {
    union { u32 u; float f; } x; x.u = ((u32)u) << 16; return x.f;
}
__device__ __forceinline__ float sigmoid5(float v) {
    return 1.0f / (1.0f + __expf(-5.0f * (v - 1.0f)));
}

__device__ __forceinline__ void gload16(const u16* g, u16* l) {
    __builtin_amdgcn_global_load_lds(
        (const __attribute__((address_space(1))) unsigned int*)(const void*)g,
        (__attribute__((address_space(3))) unsigned int*)(void*)l, 16, 0, 0);
}

// ---------- Pre-pass: Bt[kt][n][slot*8 + k&7] bf16 + wrelu ----------
__global__ void convert_W(const float* __restrict__ w_ih,
                          const float* __restrict__ w_ho,
                          u16* __restrict__ Bt, float* __restrict__ wrelu) {
    if (blockIdx.x == NK * 32) {
        for (int i = threadIdx.x; i < NH * NO; i += 256)
            wrelu[i] = fmaxf(0.f, w_ho[i]);
        return;
    }
    const int k = blockIdx.x;           // 0..799
    const int n = threadIdx.x;          // 0..255
    const float f = (k < NIN) ? fmaxf(0.f, w_ih[k * NH + n]) : 0.f;
    const int kt = k >> 5, kk = k & 31;
    const int slot = (kk >> 3) ^ (n & 3) ^ ((n >> 2) & 3);
    Bt[(size_t)kt * 8192 + n * 32 + slot * 8 + (kk & 7)] = f2bf(f);
}

// ---------- hidden GEMM (R9 verbatim) ----------
__global__ __launch_bounds__(512, 4) void gemm_hidden(
    const float* __restrict__ spikes,   // [128][784][500] f32
    const u16* __restrict__ Bt,         // [25][256][32] bf16 swizzled
    u16* __restrict__ Ih)               // [128][256][512] bf16
{
    __shared__ u16 SH[24576];           // 48KB
    u16* AS0 = SH;
    u16* AS1 = SH + 4096;
    u16* BS0 = SH + 8192;
    u16* BS1 = SH + 16384;

    const int tid = threadIdx.x;
    const int b   = blockIdx.x >> 2;
    const int tq  = blockIdx.x & 3;
    const int t0  = tq * 128;

    const int kp = tid >> 5, tg = tid & 31;
    const int tloc = t0 + tg * 4;
    const int koff = (2 * kp) & 7;
    const int oct  = kp >> 2;
    const bool t_ok = (tloc <= 496);
    const float* sbase = spikes + (size_t)b * (NIN * T_) + tloc;

    const int lane = tid & 63, wid = tid >> 6;
    const int wm = wid >> 2, wn = wid & 3;
    const int lg = lane >> 4, lr = lane & 15;
    int aOff[4], bOff[4];
#pragma unroll
    for (int mi = 0; mi < 4; ++mi) {
        const int m = wm * 64 + mi * 16 + lr;
        aOff[mi] = m * 32 + ((lg ^ (m & 3) ^ ((m >> 2) & 3)) << 3);
    }
#pragma unroll
    for (int ni = 0; ni < 4; ++ni) {
        const int n = wn * 64 + ni * 16 + lr;
        bOff[ni] = n * 32 + ((lg ^ (n & 3) ^ ((n >> 2) & 3)) << 3);
    }

    floatx4 acc[4][4];
#pragma unroll
    for (int i = 0; i < 4; ++i)
#pragma unroll
        for (int j = 0; j < 4; ++j) acc[i][j] = (floatx4)0.f;

#define LOADA(v0, v1, itv) {                                                   \
        const int gk = (itv) * 32 + 2 * kp;                                    \
        const bool ok0 = t_ok && (gk < NIN);                                   \
        const bool ok1 = t_ok && (gk + 1 < NIN);                               \
        const float* p0 = ok0 ? (sbase + (size_t)gk * T_) : sbase;             \
        const float* p1 = ok1 ? (sbase + (size_t)(gk + 1) * T_) : sbase;       \
        floatx4 u0 = *(const floatx4*)p0;                                      \
        floatx4 u1 = *(const floatx4*)p1;                                      \
        v0 = ok0 ? u0 : (floatx4)0.f;                                          \
        v1 = ok1 ? u1 : (floatx4)0.f; }

#define WRITEA(ASX, v0, v1) { _Pragma("unroll") for (int j = 0; j < 4; ++j) {  \
        const int m = tg * 4 + j;                                              \
        const int slot = oct ^ (m & 3) ^ ((m >> 2) & 3);                       \
        const u32 pk = (u32)f2bf(v0[j]) | ((u32)f2bf(v1[j]) << 16);            \
        *(u32*)&(ASX)[m * 32 + slot * 8 + koff] = pk; } }

#define STAGEB(BSX, itv) { const u16* src = Bt + (size_t)(itv) * 8192;         \
        gload16(src + tid * 8,        (BSX) + tid * 8);                        \
        gload16(src + 4096 + tid * 8, (BSX) + 4096 + tid * 8); }

#define MFMAIT(ASX, BSX) { shortx8 af[4], bf[4];                               \
        _Pragma("unroll") for (int mi = 0; mi < 4; ++mi)                       \
            af[mi] = *(const shortx8*)&(ASX)[aOff[mi]];                        \
        _Pragma("unroll") for (int ni = 0; ni < 4; ++ni)                       \
            bf[ni] = *(const shortx8*)&(BSX)[bOff[ni]];                        \
        _Pragma("unroll") for (int mi = 0; mi < 4; ++mi)                       \
        _Pragma("unroll") for (int ni = 0; ni < 4; ++ni)                       \
            acc[mi][ni] = __builtin_amdgcn_mfma_f32_16x16x32_bf16(             \
                af[mi], bf[ni], acc[mi][ni], 0, 0, 0); }

    floatx4 vaP0, vaP1, vaQ0, vaQ1;

    LOADA(vaP0, vaP1, 0);
    WRITEA(AS0, vaP0, vaP1);
    STAGEB(BS0, 0);
    LOADA(vaQ0, vaQ1, 1);
    __syncthreads();

    for (int it = 0; it < 24; it += 2) {
        WRITEA(AS1, vaQ0, vaQ1);
        STAGEB(BS1, it + 1);
        LOADA(vaP0, vaP1, it + 2);
        MFMAIT(AS0, BS0);
        __syncthreads();
        WRITEA(AS0, vaP0, vaP1);
        STAGEB(BS0, it + 2);
        LOADA(vaQ0, vaQ1, it + 3);
        MFMAIT(AS1, BS1);
        __syncthreads();
    }
    MFMAIT(AS0, BS0);
    __syncthreads();

    u16* Cs = SH;
#pragma unroll
    for (int h = 0; h < 2; ++h) {
        if (wm == h) {
#pragma unroll
            for (int mi = 0; mi < 4; ++mi)
#pragma unroll
                for (int rr = 0; rr < 2; ++rr) {
                    const int mloc = mi * 16 + lg * 4 + rr * 2;
#pragma unroll
                    for (int ni = 0; ni < 4; ++ni) {
                        const int n = wn * 64 + ni * 16 + lr;
                        const u32 pk = (u32)f2bf(acc[mi][ni][rr * 2]) |
                                       ((u32)f2bf(acc[mi][ni][rr * 2 + 1]) << 16);
                        *(u32*)&Cs[n * 64 + (mloc ^ ((n & 7) << 3))] = pk;
                    }
                }
        }
        __syncthreads();
        {
            const int n = tid >> 1, mh = tid & 1;
            u16* gdst = Ih + ((size_t)b * 256 + n) * 512 + t0 + h * 64 + mh * 32;
#pragma unroll
            for (int j = 0; j < 4; ++j) {
                const uint4 v = *(const uint4*)&Cs[n * 64 + ((mh * 32 + 8 * j) ^ ((n & 7) << 3))];
                *(uint4*)(gdst + 8 * j) = v;
            }
        }
        __syncthreads();
    }
#undef LOADA
#undef WRITEA
#undef STAGEB
#undef MFMAIT
}

// ---------- parallel hidden LIF scan (in place) ----------
__global__ __launch_bounds__(512) void scan_h(u16* __restrict__ Ih) {
    const int lane = threadIdx.x & 63;
    const int row  = blockIdx.x * 8 + (threadIdx.x >> 6);
    u16* p = Ih + (size_t)row * 512 + lane * 8;
    shortx8 xv = *(const shortx8*)p;
    float I[8];
#pragma unroll
    for (int j = 0; j < 8; ++j) I[j] = bf2f((u16)xv[j]);
    float z = 0.f;
#pragma unroll
    for (int j = 0; j < 8; ++j) z += (I[j] - z) * 0.1f;
    float A = 0.43046721f, Bv = z;                 // 0.9^8
#pragma unroll
    for (int d = 1; d < 64; d <<= 1) {
        const float Au = __shfl_up(A, d);
        const float Bu = __shfl_up(Bv, d);
        if (lane >= d) { Bv = fmaf(A, Bu, Bv); A *= Au; }
    }
    float v = __shfl_up(Bv, 1);
    if (lane == 0) v = 0.f;
#pragma unroll
    for (int j = 0; j < 8; ++j) {
        v += (I[j] - v) * 0.1f;
        xv[j] = (short)f2bf(sigmoid5(v));
    }
    *(shortx8*)p = xv;
}

// ---------- output GEMM: Io[b][t][o] = sum_h s[b][h][t] * wrelu[h][o] ----------
// 512 blocks = (b, tq); 512 thr = (hq 0..3, tl 0..127): thread sums its
// h-quarter (64 coalesced iters x 10 FMA); LDS [4][128][10] reduce.
__global__ __launch_bounds__(512) void gemm_out(
    const u16* __restrict__ s,          // [128][256][512] bf16
    const float* __restrict__ wr,       // [256][10] relu'd f32
    float* __restrict__ Io)             // [128][500][10] f32
{
    __shared__ float P[4][128][NO];     // 20KB
    const int tid = threadIdx.x;
    const int b   = blockIdx.x >> 2;
    const int tq  = blockIdx.x & 3;
    const int hq  = tid >> 7;           // 0..3
    const int tl  = tid & 127;
    const int t   = tq * 128 + tl;

    float acc[NO];
#pragma unroll
    for (int o = 0; o < NO; ++o) acc[o] = 0.f;
    const u16* sb = s + ((size_t)b * NH + hq * 64) * 512 + t;
    const float* wb = wr + hq * 64 * NO;
#pragma unroll 4
    for (int h = 0; h < 64; ++h) {
        const float sv = bf2f(sb[h * 512]);
#pragma unroll
        for (int o = 0; o < NO; ++o) acc[o] = fmaf(sv, wb[h * NO + o], acc[o]);
    }
#pragma unroll
    for (int o = 0; o < NO; ++o) P[hq][tl][o] = acc[o];
    __syncthreads();

    // reduce 4 partials; 1280 outputs over 512 threads
    for (int i = tid; i < 128 * NO; i += 512) {
        const int tt = i / NO, o = i - tt * NO;
        const int tg = tq * 128 + tt;
        if (tg < T_)
            Io[((size_t)b * T_ + tg) * NO + o] =
                P[0][tt][o] + P[1][tt][o] + P[2][tt][o] + P[3][tt][o];
    }
}

// ---------- output LIF scan (segmented parallel, proven) ----------
__global__ __launch_bounds__(256) void lif_out(
    const float* __restrict__ IoG,      // [128][500][10] f32
    float* __restrict__ out)
{
    __shared__ float Io[T_ * NO];       // 20KB
    __shared__ float vend[25][NO], vstart[25][NO], psum[25][NO];
    const int b = blockIdx.x, tid = threadIdx.x;

    for (int i = tid; i < T_ * NO; i += 256)
        Io[i] = IoG[(size_t)b * (T_ * NO) + i];
    __syncthreads();

    const int seg = tid / NO, o = tid - seg * NO;
    if (tid < 250) {
        float v = 0.f;
#pragma unroll
        for (int j = 0; j < 20; ++j)
            v += (Io[(seg * 20 + j) * NO + o] - v) * 0.1f;
        vend[seg][o] = v;
    }
    __syncthreads();
    if (tid < NO) {
        float vs = 0.f;
#pragma unroll
        for (int sg = 0; sg < 25; ++sg) {
            vstart[sg][tid] = vs;
            vs = vend[sg][tid] + 0.12157665459f * vs;   // 0.9^20
        }
    }
    __syncthreads();
    if (tid < 250) {
        float v = vstart[seg][o], ps = 0.f;
#pragma unroll
        for (int j = 0; j < 20; ++j) {
            const int t = seg * 20 + j;
            v += (Io[t * NO + o] - v) * 0.1f;
            const float sv = sigmoid5(v);
            out[(size_t)b * (NO * T_) + (size_t)o * T_ + t] = sv;
            ps += sv;
        }
        psum[seg][o] = ps;
    }
    __syncthreads();
    if (tid < NO) {
        float tot = 0.f;
#pragma unroll
        for (int sg = 0; sg < 25; ++sg) tot += psum[sg][tid];
        out[(size_t)(B_ * NO) * T_ + b * NO + tid] = tot * (1.0f / T_);
    }
}

extern "C" void kernel_launch(void* const* d_in, const int* in_sizes, int n_in,
                              void* d_out, int out_size, void* d_ws, size_t ws_size,
                              hipStream_t stream) {
    (void)in_sizes; (void)n_in; (void)out_size; (void)ws_size;
    const float* spikes = (const float*)d_in[0];   // [128][784][500]
    const float* w_ih   = (const float*)d_in[1];   // [784][256]
    const float* w_ho   = (const float*)d_in[2];   // [256][10]
    float* out = (float*)d_out;

    float* wrelu = (float*)d_ws;                            // 10KB @0
    u16*   Bt    = (u16*)((char*)d_ws + 16384);             // 400KB
    u16*   Ih    = (u16*)((char*)d_ws + 524288);            // 33.55MB
    float* Io    = (float*)((char*)d_ws + 524288 + 33554432); // 2.56MB

    convert_W  <<<NK * 32 + 1, 256, 0, stream>>>(w_ih, w_ho, Bt, wrelu);
    gemm_hidden<<<512, 512, 0, stream>>>(spikes, Bt, Ih);
    scan_h     <<<4096, 512, 0, stream>>>(Ih);
    gemm_out   <<<512, 512, 0, stream>>>(Ih, wrelu, Io);
    lif_out    <<<B_, 256, 0, stream>>>(Io, out);
}

// Round 15
// 95.488 us; speedup vs baseline: 2.0447x; 1.0474x over previous
//
#include <hip/hip_runtime.h>

// LIF net on MI355X.  R15 = R14 tail + 256x256 read-once gemm w/ 1KB A-runs.
//  1. convert_W: Bt[25][256][32] bf16 (relu, slot-swizzled, K-pad 800) + wrelu
//  2. gemm_hidden: 256 blocks (b, t-half) x 1024 thr (16 waves, 4wm x 4wn),
//     tile 256m x 256n, BK=32.  Wave A-load = one 1KB contiguous t-run.
//     LDS 64KB: As dbuf 2x16KB (slot-swizzled) + Bs dbuf 2x16KB (gload16).
//     Counted barrier: vmcnt(2) retires B, A prefetch stays in flight.
//  3. scan_h: wave-per-row parallel LIF scan (shfl_up affine composition)
//  4. gemm_out: 512 blocks, LDS reduce -> Io[b][t][o] f32
//  5. lif_out: per-b segmented v_o scan -> outputs
// ws: wrelu @0 (10KB) | Bt @16KB (400KB) | Ih @512KB (33.55MB) | Io (2.56MB)

typedef __attribute__((ext_vector_type(4))) float  floatx4;
typedef __attribute__((ext_vector_type(8))) short  shortx8;
typedef unsigned short u16;
typedef unsigned int   u32;

#define B_   128
#define NIN  784
#define NH   256
#define NO   10
#define T_   500
#define NK   25            // K padded to 800, tiles of 32

__device__ __forceinline__ u16 f2bf(float f) {
    union { float f; u32 u; } x; x.f = f;
    u32 r = x.u + 0x7FFFu + ((x.u >> 16) & 1u);   // RNE
    return (u16)(r >> 16);
}
__device__ __forceinline__ float bf2f(u16 u) {
    union { u32 u; float f; } x; x.u = ((u32)u) << 16; return x.f;
}
__device__ __forceinline__ float sigmoid5(float v) {
    return 1.0f / (1.0f + __expf(-5.0f * (v - 1.0f)));
}

__device__ __forceinline__ void gload16(const u16* g, u16* l) {
    __builtin_amdgcn_global_load_lds(
        (const __attribute__((address_space(1))) unsigned int*)(const void*)g,
        (__attribute__((address_space(3))) unsigned int*)(void*)l, 16, 0, 0);
}

// ---------- Pre-pass: Bt[kt][n][slot*8 + k&7] bf16 + wrelu ----------
__global__ void convert_W(const float* __restrict__ w_ih,
                          const float* __restrict__ w_ho,
                          u16* __restrict__ Bt, float* __restrict__ wrelu) {
    if (blockIdx.x == NK * 32) {
        for (int i = threadIdx.x; i < NH * NO; i += 256)
            wrelu[i] = fmaxf(0.f, w_ho[i]);
        return;
    }
    const int k = blockIdx.x;           // 0..799
    const int n = threadIdx.x;          // 0..255
    const float f = (k < NIN) ? fmaxf(0.f, w_ih[k * NH + n]) : 0.f;
    const int kt = k >> 5, kk = k & 31;
    const int slot = (kk >> 3) ^ (n & 3) ^ ((n >> 2) & 3);
    Bt[(size_t)kt * 8192 + n * 32 + slot * 8 + (kk & 7)] = f2bf(f);
}

// ---------- hidden GEMM: 256m x 256n, 1KB A-runs, counted barriers ----------
__global__ __launch_bounds__(1024, 4) void gemm_hidden(
    const float* __restrict__ spikes,   // [128][784][500] f32
    const u16* __restrict__ Bt,         // [25][256][32] bf16 swizzled
    u16* __restrict__ Ih)               // [128][256][512] bf16
{
    __shared__ u16 SH[32768];           // 64KB
    u16* AS0 = SH;                      // 8192 u16 = 16KB each
    u16* AS1 = SH + 8192;
    u16* BS0 = SH + 16384;
    u16* BS1 = SH + 24576;

    const int tid = threadIdx.x;
    const int b   = blockIdx.x >> 1;
    const int th  = blockIdx.x & 1;
    const int t0  = th * 256;

    // A staging: wave = 1 k-row pair; kq=tid>>6 (0..15) -> k=2kq,2kq+1;
    // tg=tid&63 -> t=t0+4tg.  Each wave-load = 64 lanes x 16B = 1KB run.
    const int kq = tid >> 6, tg = tid & 63;
    const int tloc = t0 + tg * 4;
    const bool t_ok = (tloc <= 496);
    const float* sbase = spikes + (size_t)b * (NIN * T_) + tloc;
    const int oct  = kq >> 2;           // k-octet 0..3
    const int koff = (2 * kq) & 7;      // 0,2,4,6

    // MFMA roles: 16 waves = 4 wm x 4 wn, wave tile 64m x 64n
    const int lane = tid & 63, wid = tid >> 6;
    const int wm = wid >> 2, wn = wid & 3;
    const int lg = lane >> 4, lr = lane & 15;
    int aOff[4], bOff[4];
#pragma unroll
    for (int mi = 0; mi < 4; ++mi) {
        const int m = wm * 64 + mi * 16 + lr;
        aOff[mi] = m * 32 + ((lg ^ (m & 3) ^ ((m >> 2) & 3)) << 3);
    }
#pragma unroll
    for (int ni = 0; ni < 4; ++ni) {
        const int n = wn * 64 + ni * 16 + lr;
        bOff[ni] = n * 32 + ((lg ^ (n & 3) ^ ((n >> 2) & 3)) << 3);
    }

    floatx4 acc[4][4];
#pragma unroll
    for (int i = 0; i < 4; ++i)
#pragma unroll
        for (int j = 0; j < 4; ++j) acc[i][j] = (floatx4)0.f;

#define LOADA(v0, v1, itv) {                                                   \
        const int gk = (itv) * 32 + 2 * kq;                                    \
        const bool ok0 = t_ok && (gk < NIN);                                   \
        const bool ok1 = t_ok && (gk + 1 < NIN);                               \
        const float* p0 = ok0 ? (sbase + (size_t)gk * T_) : sbase;             \
        const float* p1 = ok1 ? (sbase + (size_t)(gk + 1) * T_) : sbase;       \
        floatx4 u0 = *(const floatx4*)p0;                                      \
        floatx4 u1 = *(const floatx4*)p1;                                      \
        v0 = ok0 ? u0 : (floatx4)0.f;                                          \
        v1 = ok1 ? u1 : (floatx4)0.f; }

#define WRITEA(ASX, v0, v1) { _Pragma("unroll") for (int j = 0; j < 4; ++j) {  \
        const int m = tg * 4 + j;                                              \
        const int slot = oct ^ (m & 3) ^ ((m >> 2) & 3);                       \
        const u32 pk = (u32)f2bf(v0[j]) | ((u32)f2bf(v1[j]) << 16);            \
        *(u32*)&(ASX)[m * 32 + slot * 8 + koff] = pk; } }

#define STAGEB(BSX, itv)                                                       \
        gload16(Bt + (size_t)(itv) * 8192 + tid * 8, (BSX) + tid * 8);

#define MFMAIT(ASX, BSX) { shortx8 af[4], bf[4];                               \
        _Pragma("unroll") for (int mi = 0; mi < 4; ++mi)                       \
            af[mi] = *(const shortx8*)&(ASX)[aOff[mi]];                        \
        _Pragma("unroll") for (int ni = 0; ni < 4; ++ni)                       \
            bf[ni] = *(const shortx8*)&(BSX)[bOff[ni]];                        \
        _Pragma("unroll") for (int mi = 0; mi < 4; ++mi)                       \
        _Pragma("unroll") for (int ni = 0; ni < 4; ++ni)                       \
            acc[mi][ni] = __builtin_amdgcn_mfma_f32_16x16x32_bf16(             \
                af[mi], bf[ni], acc[mi][ni], 0, 0, 0); }

// counted barrier: retires B stage (oldest), leaves A prefetch (2) in flight
#define CBAR2 { asm volatile("s_waitcnt vmcnt(2) lgkmcnt(0)" ::: "memory");    \
                __builtin_amdgcn_s_barrier(); }
#define LBAR  { asm volatile("s_waitcnt lgkmcnt(0)" ::: "memory");             \
                __builtin_amdgcn_s_barrier(); }

    floatx4 vaP0, vaP1;

    // prologue: A0 -> AS0 (compiler-waited), B0 issued, A1 in flight
    LOADA(vaP0, vaP1, 0);
    WRITEA(AS0, vaP0, vaP1);
    STAGEB(BS0, 0);
    LOADA(vaP0, vaP1, 1);
    CBAR2;                              // B0 done; A1 flying

    // body: 24 iters (12 x 2-unroll).  Iter it: compute tile it (cur),
    // stage B(it+1) + write A(it+1) to nxt, prefetch A(it+2).
    for (int it = 0; it < 24; it += 2) {
        STAGEB(BS1, it + 1);
        WRITEA(AS1, vaP0, vaP1);        // waits A(it+1) only (older than B)
        { const int nv = (it + 2 < 24) ? (it + 2) : 24;
          LOADA(vaP0, vaP1, nv); }
        MFMAIT(AS0, BS0);
        CBAR2;                          // B(it+1) done; A(it+2) flying

        STAGEB(BS0, it + 2);
        WRITEA(AS0, vaP0, vaP1);
        { const int nv = (it + 3 < 24) ? (it + 3) : 24;
          LOADA(vaP0, vaP1, nv); }
        MFMAIT(AS1, BS1);
        CBAR2;
    }
    MFMAIT(AS0, BS0);                   // tile 24
    LBAR;                               // LDS reads done; SH free for Cs

    // ---- epilogue: 4 wm-rounds via Cs[256 n][64 m] (32KB, aliases SH) ----
    u16* Cs = SH;
#pragma unroll
    for (int h = 0; h < 4; ++h) {
        if (wm == h) {
#pragma unroll
            for (int mi = 0; mi < 4; ++mi)
#pragma unroll
                for (int rr = 0; rr < 2; ++rr) {
                    const int mloc = mi * 16 + lg * 4 + rr * 2;
#pragma unroll
                    for (int ni = 0; ni < 4; ++ni) {
                        const int n = wn * 64 + ni * 16 + lr;
                        const u32 pk = (u32)f2bf(acc[mi][ni][rr * 2]) |
                                       ((u32)f2bf(acc[mi][ni][rr * 2 + 1]) << 16);
                        *(u32*)&Cs[n * 64 + (mloc ^ ((n & 7) << 3))] = pk;
                    }
                }
        }
        LBAR;
        {
            const int n = tid >> 2, ms = tid & 3;
            u16* gdst = Ih + ((size_t)b * 256 + n) * 512 + t0 + h * 64 + ms * 16;
#pragma unroll
            for (int j = 0; j < 2; ++j) {
                const uint4 v = *(const uint4*)&Cs[n * 64 +
                                ((ms * 16 + j * 8) ^ ((n & 7) << 3))];
                *(uint4*)(gdst + j * 8) = v;
            }
        }
        LBAR;
    }
#undef LOADA
#undef WRITEA
#undef STAGEB
#undef MFMAIT
#undef CBAR2
#undef LBAR
}

// ---------- parallel hidden LIF scan (in place) ----------
__global__ __launch_bounds__(512) void scan_h(u16* __restrict__ Ih) {
    const int lane = threadIdx.x & 63;
    const int row  = blockIdx.x * 8 + (threadIdx.x >> 6);
    u16* p = Ih + (size_t)row * 512 + lane * 8;
    shortx8 xv = *(const shortx8*)p;
    float I[8];
#pragma unroll
    for (int j = 0; j < 8; ++j) I[j] = bf2f((u16)xv[j]);
    float z = 0.f;
#pragma unroll
    for (int j = 0; j < 8; ++j) z += (I[j] - z) * 0.1f;
    float A = 0.43046721f, Bv = z;                 // 0.9^8
#pragma unroll
    for (int d = 1; d < 64; d <<= 1) {
        const float Au = __shfl_up(A, d);
        const float Bu = __shfl_up(Bv, d);
        if (lane >= d) { Bv = fmaf(A, Bu, Bv); A *= Au; }
    }
    float v = __shfl_up(Bv, 1);
    if (lane == 0) v = 0.f;
#pragma unroll
    for (int j = 0; j < 8; ++j) {
        v += (I[j] - v) * 0.1f;
        xv[j] = (short)f2bf(sigmoid5(v));
    }
    *(shortx8*)p = xv;
}

// ---------- output GEMM: Io[b][t][o] = sum_h s[b][h][t] * wrelu[h][o] ----------
__global__ __launch_bounds__(512) void gemm_out(
    const u16* __restrict__ s,          // [128][256][512] bf16
    const float* __restrict__ wr,       // [256][10] relu'd f32
    float* __restrict__ Io)             // [128][500][10] f32
{
    __shared__ float P[4][128][NO];     // 20KB
    const int tid = threadIdx.x;
    const int b   = blockIdx.x >> 2;
    const int tq  = blockIdx.x & 3;
    const int hq  = tid >> 7;           // 0..3
    const int tl  = tid & 127;
    const int t   = tq * 128 + tl;

    float acc[NO];
#pragma unroll
    for (int o = 0; o < NO; ++o) acc[o] = 0.f;
    const u16* sb = s + ((size_t)b * NH + hq * 64) * 512 + t;
    const float* wb = wr + hq * 64 * NO;
#pragma unroll 4
    for (int h = 0; h < 64; ++h) {
        const float sv = bf2f(sb[h * 512]);
#pragma unroll
        for (int o = 0; o < NO; ++o) acc[o] = fmaf(sv, wb[h * NO + o], acc[o]);
    }
#pragma unroll
    for (int o = 0; o < NO; ++o) P[hq][tl][o] = acc[o];
    __syncthreads();

    for (int i = tid; i < 128 * NO; i += 512) {
        const int tt = i / NO, o = i - tt * NO;
        const int tg = tq * 128 + tt;
        if (tg < T_)
            Io[((size_t)b * T_ + tg) * NO + o] =
                P[0][tt][o] + P[1][tt][o] + P[2][tt][o] + P[3][tt][o];
    }
}

// ---------- output LIF scan (segmented parallel) ----------
__global__ __launch_bounds__(256) void lif_out(
    const float* __restrict__ IoG,      // [128][500][10] f32
    float* __restrict__ out)
{
    __shared__ float Io[T_ * NO];       // 20KB
    __shared__ float vend[25][NO], vstart[25][NO], psum[25][NO];
    const int b = blockIdx.x, tid = threadIdx.x;

    for (int i = tid; i < T_ * NO; i += 256)
        Io[i] = IoG[(size_t)b * (T_ * NO) + i];
    __syncthreads();

    const int seg = tid / NO, o = tid - seg * NO;
    if (tid < 250) {
        float v = 0.f;
#pragma unroll
        for (int j = 0; j < 20; ++j)
            v += (Io[(seg * 20 + j) * NO + o] - v) * 0.1f;
        vend[seg][o] = v;
    }
    __syncthreads();
    if (tid < NO) {
        float vs = 0.f;
#pragma unroll
        for (int sg = 0; sg < 25; ++sg) {
            vstart[sg][tid] = vs;
            vs = vend[sg][tid] + 0.12157665459f * vs;   // 0.9^20
        }
    }
    __syncthreads();
    if (tid < 250) {
        float v = vstart[seg][o], ps = 0.f;
#pragma unroll
        for (int j = 0; j < 20; ++j) {
            const int t = seg * 20 + j;
            v += (Io[t * NO + o] - v) * 0.1f;
            const float sv = sigmoid5(v);
            out[(size_t)b * (NO * T_) + (size_t)o * T_ + t] = sv;
            ps += sv;
        }
        psum[seg][o] = ps;
    }
    __syncthreads();
    if (tid < NO) {
        float tot = 0.f;
#pragma unroll
        for (int sg = 0; sg < 25; ++sg) tot += psum[sg][tid];
        out[(size_t)(B_ * NO) * T_ + b * NO + tid] = tot * (1.0f / T_);
    }
}

extern "C" void kernel_launch(void* const* d_in, const int* in_sizes, int n_in,
                              void* d_out, int out_size, void* d_ws, size_t ws_size,
                              hipStream_t stream) {
    (void)in_sizes; (void)n_in; (void)out_size; (void)ws_size;
    const float* spikes = (const float*)d_in[0];   // [128][784][500]
    const float* w_ih   = (const float*)d_in[1];   // [784][256]
    const float* w_ho   = (const float*)d_in[2];   // [256][10]
    float* out = (float*)d_out;

    float* wrelu = (float*)d_ws;                              // 10KB @0
    u16*   Bt    = (u16*)((char*)d_ws + 16384);               // 400KB
    u16*   Ih    = (u16*)((char*)d_ws + 524288);              // 33.55MB
    float* Io    = (float*)((char*)d_ws + 524288 + 33554432); // 2.56MB

    convert_W  <<<NK * 32 + 1, 256, 0, stream>>>(w_ih, w_ho, Bt, wrelu);
    gemm_hidden<<<256, 1024, 0, stream>>>(spikes, Bt, Ih);
    scan_h     <<<4096, 512, 0, stream>>>(Ih);
    gemm_out   <<<512, 512, 0, stream>>>(Ih, wrelu, Io);
    lif_out    <<<B_, 256, 0, stream>>>(Io, out);
}

// Round 16
// 82.620 us; speedup vs baseline: 2.3631x; 1.1557x over previous
//
#include <hip/hip_runtime.h>

// LIF net on MI355X.  R16 = R15 gemm (+XCD pair-swizzle) + fused scan+dot tail.
//  1. convert_W: Bt[25][256][32] bf16 (relu, slot-swizzled, K-pad 800) + wrelu
//  2. gemm_hidden: 256 blocks (b, t-half) x 1024 thr, tile 256m x 256n, BK=32,
//     1KB A-runs, counted vmcnt(2) barriers; XCD swizzle pairs (b,0),(b,1)
//     on one XCD.  -> Ih[b][h][512] bf16
//  3. scan_dot: 512 blocks (b, h-group of 64) x 512 thr: wave-parallel LIF
//     scan (8 rows/wave) -> s bf16 in LDS [64][520] -> MFMA vs w_ho frags
//     -> partial IoP[b][t][4][10] f32.  (replaces scan_h + gemm_out)
//  4. lif_out: per-b: sum 4 partials -> segmented v_o scan -> outputs
// ws: wrelu @0 | Bt @16KB | Ih @512KB (33.55MB) | IoP @34.08MB (10.49MB)

typedef __attribute__((ext_vector_type(4))) float  floatx4;
typedef __attribute__((ext_vector_type(8))) short  shortx8;
typedef unsigned short u16;
typedef unsigned int   u32;

#define B_   128
#define NIN  784
#define NH   256
#define NO   10
#define T_   500
#define NK   25            // K padded to 800, tiles of 32
#define SROW 520           // sbuf row stride (u16): 1040B, 16B-aligned rows

__device__ __forceinline__ u16 f2bf(float f) {
    union { float f; u32 u; } x; x.f = f;
    u32 r = x.u + 0x7FFFu + ((x.u >> 16) & 1u);   // RNE
    return (u16)(r >> 16);
}
__device__ __forceinline__ float bf2f(u16 u) {
    union { u32 u; float f; } x; x.u = ((u32)u) << 16; return x.f;
}
__device__ __forceinline__ float sigmoid5(float v) {
    return 1.0f / (1.0f + __expf(-5.0f * (v - 1.0f)));
}

__device__ __forceinline__ void gload16(const u16* g, u16* l) {
    __builtin_amdgcn_global_load_lds(
        (const __attribute__((address_space(1))) unsigned int*)(const void*)g,
        (__attribute__((address_space(3))) unsigned int*)(void*)l, 16, 0, 0);
}

// ---------- Pre-pass: Bt[kt][n][slot*8 + k&7] bf16 + wrelu ----------
__global__ void convert_W(const float* __restrict__ w_ih,
                          const float* __restrict__ w_ho,
                          u16* __restrict__ Bt, float* __restrict__ wrelu) {
    if (blockIdx.x == NK * 32) {
        for (int i = threadIdx.x; i < NH * NO; i += 256)
            wrelu[i] = fmaxf(0.f, w_ho[i]);
        return;
    }
    const int k = blockIdx.x;           // 0..799
    const int n = threadIdx.x;          // 0..255
    const float f = (k < NIN) ? fmaxf(0.f, w_ih[k * NH + n]) : 0.f;
    const int kt = k >> 5, kk = k & 31;
    const int slot = (kk >> 3) ^ (n & 3) ^ ((n >> 2) & 3);
    Bt[(size_t)kt * 8192 + n * 32 + slot * 8 + (kk & 7)] = f2bf(f);
}

// ---------- hidden GEMM: 256m x 256n, 1KB A-runs, counted barriers ----------
__global__ __launch_bounds__(1024, 4) void gemm_hidden(
    const float* __restrict__ spikes,   // [128][784][500] f32
    const u16* __restrict__ Bt,         // [25][256][32] bf16 swizzled
    u16* __restrict__ Ih)               // [128][256][512] bf16
{
    __shared__ u16 SH[32768];           // 64KB
    u16* AS0 = SH;                      // 8192 u16 = 16KB each
    u16* AS1 = SH + 8192;
    u16* BS0 = SH + 16384;
    u16* BS1 = SH + 24576;

    const int tid = threadIdx.x;
    // XCD pair-swizzle (grid 256 = 32 slots x 8 XCDs, bijective):
    // dispatch i -> XCD i%8; (b,th=0),(b,th=1) = slots 2j,2j+1 -> same XCD.
    const int xcd  = blockIdx.x & 7;
    const int slot = blockIdx.x >> 3;   // 0..31
    const int b    = xcd * 16 + (slot >> 1);
    const int th   = slot & 1;
    const int t0   = th * 256;

    // A staging: kq=tid>>6 (0..15) -> k=2kq,2kq+1; tg=tid&63 -> t=t0+4tg.
    const int kq = tid >> 6, tg = tid & 63;
    const int tloc = t0 + tg * 4;
    const bool t_ok = (tloc <= 496);
    const float* sbase = spikes + (size_t)b * (NIN * T_) + tloc;
    const int oct  = kq >> 2;
    const int koff = (2 * kq) & 7;

    const int lane = tid & 63, wid = tid >> 6;
    const int wm = wid >> 2, wn = wid & 3;
    const int lg = lane >> 4, lr = lane & 15;
    int aOff[4], bOff[4];
#pragma unroll
    for (int mi = 0; mi < 4; ++mi) {
        const int m = wm * 64 + mi * 16 + lr;
        aOff[mi] = m * 32 + ((lg ^ (m & 3) ^ ((m >> 2) & 3)) << 3);
    }
#pragma unroll
    for (int ni = 0; ni < 4; ++ni) {
        const int n = wn * 64 + ni * 16 + lr;
        bOff[ni] = n * 32 + ((lg ^ (n & 3) ^ ((n >> 2) & 3)) << 3);
    }

    floatx4 acc[4][4];
#pragma unroll
    for (int i = 0; i < 4; ++i)
#pragma unroll
        for (int j = 0; j < 4; ++j) acc[i][j] = (floatx4)0.f;

#define LOADA(v0, v1, itv) {                                                   \
        const int gk = (itv) * 32 + 2 * kq;                                    \
        const bool ok0 = t_ok && (gk < NIN);                                   \
        const bool ok1 = t_ok && (gk + 1 < NIN);                               \
        const float* p0 = ok0 ? (sbase + (size_t)gk * T_) : sbase;             \
        const float* p1 = ok1 ? (sbase + (size_t)(gk + 1) * T_) : sbase;       \
        floatx4 u0 = *(const floatx4*)p0;                                      \
        floatx4 u1 = *(const floatx4*)p1;                                      \
        v0 = ok0 ? u0 : (floatx4)0.f;                                          \
        v1 = ok1 ? u1 : (floatx4)0.f; }

#define WRITEA(ASX, v0, v1) { _Pragma("unroll") for (int j = 0; j < 4; ++j) {  \
        const int m = tg * 4 + j;                                              \
        const int slt = oct ^ (m & 3) ^ ((m >> 2) & 3);                        \
        const u32 pk = (u32)f2bf(v0[j]) | ((u32)f2bf(v1[j]) << 16);            \
        *(u32*)&(ASX)[m * 32 + slt * 8 + koff] = pk; } }

#define STAGEB(BSX, itv)                                                       \
        gload16(Bt + (size_t)(itv) * 8192 + tid * 8, (BSX) + tid * 8);

#define MFMAIT(ASX, BSX) { shortx8 af[4], bf[4];                               \
        _Pragma("unroll") for (int mi = 0; mi < 4; ++mi)                       \
            af[mi] = *(const shortx8*)&(ASX)[aOff[mi]];                        \
        _Pragma("unroll") for (int ni = 0; ni < 4; ++ni)                       \
            bf[ni] = *(const shortx8*)&(BSX)[bOff[ni]];                        \
        _Pragma("unroll") for (int mi = 0; mi < 4; ++mi)                       \
        _Pragma("unroll") for (int ni = 0; ni < 4; ++ni)                       \
            acc[mi][ni] = __builtin_amdgcn_mfma_f32_16x16x32_bf16(             \
                af[mi], bf[ni], acc[mi][ni], 0, 0, 0); }

#define CBAR2 { asm volatile("s_waitcnt vmcnt(2) lgkmcnt(0)" ::: "memory");    \
                __builtin_amdgcn_s_barrier(); }
#define LBAR  { asm volatile("s_waitcnt lgkmcnt(0)" ::: "memory");             \
                __builtin_amdgcn_s_barrier(); }

    floatx4 vaP0, vaP1;

    LOADA(vaP0, vaP1, 0);
    WRITEA(AS0, vaP0, vaP1);
    STAGEB(BS0, 0);
    LOADA(vaP0, vaP1, 1);
    CBAR2;

    for (int it = 0; it < 24; it += 2) {
        STAGEB(BS1, it + 1);
        WRITEA(AS1, vaP0, vaP1);
        { const int nv = (it + 2 < 24) ? (it + 2) : 24;
          LOADA(vaP0, vaP1, nv); }
        MFMAIT(AS0, BS0);
        CBAR2;

        STAGEB(BS0, it + 2);
        WRITEA(AS0, vaP0, vaP1);
        { const int nv = (it + 3 < 24) ? (it + 3) : 24;
          LOADA(vaP0, vaP1, nv); }
        MFMAIT(AS1, BS1);
        CBAR2;
    }
    MFMAIT(AS0, BS0);                   // tile 24
    LBAR;

    // epilogue: 4 wm-rounds via Cs[256 n][64 m] (32KB, aliases SH)
    u16* Cs = SH;
#pragma unroll
    for (int h = 0; h < 4; ++h) {
        if (wm == h) {
#pragma unroll
            for (int mi = 0; mi < 4; ++mi)
#pragma unroll
                for (int rr = 0; rr < 2; ++rr) {
                    const int mloc = mi * 16 + lg * 4 + rr * 2;
#pragma unroll
                    for (int ni = 0; ni < 4; ++ni) {
                        const int n = wn * 64 + ni * 16 + lr;
                        const u32 pk = (u32)f2bf(acc[mi][ni][rr * 2]) |
                                       ((u32)f2bf(acc[mi][ni][rr * 2 + 1]) << 16);
                        *(u32*)&Cs[n * 64 + (mloc ^ ((n & 7) << 3))] = pk;
                    }
                }
        }
        LBAR;
        {
            const int n = tid >> 2, ms = tid & 3;
            u16* gdst = Ih + ((size_t)b * 256 + n) * 512 + t0 + h * 64 + ms * 16;
#pragma unroll
            for (int j = 0; j < 2; ++j) {
                const uint4 v = *(const uint4*)&Cs[n * 64 +
                                ((ms * 16 + j * 8) ^ ((n & 7) << 3))];
                *(uint4*)(gdst + j * 8) = v;
            }
        }
        LBAR;
    }
#undef LOADA
#undef WRITEA
#undef STAGEB
#undef MFMAIT
#undef CBAR2
#undef LBAR
}

// ---------- fused: parallel hidden LIF scan + output dot ----------
// 512 blocks = (b, hg of 64 h); 512 thr = 8 waves.  Phase 1: wave scans 8
// rows (proven affine shfl), one ds_write_b128 per row into sbuf[64][520].
// Phase 2: MFMA 16x16x32 (m=t, k=h local 64, n=o) -> IoP[b][t][hg][o].
__global__ __launch_bounds__(512, 2) void scan_dot(
    const u16* __restrict__ Ih,         // [128][256][512] bf16
    const float* __restrict__ wr,       // [256][10] relu'd f32
    float* __restrict__ IoP)            // [128][512][4][10] f32
{
    __shared__ u16 sbuf[64 * SROW];     // 66.6KB
    const int tid = threadIdx.x;
    const int hg  = blockIdx.x & 3;
    const int b   = blockIdx.x >> 2;
    const int h0  = hg * 64;
    const int lane = tid & 63, w = tid >> 6;

    // ---- phase 1: scan 8 rows per wave ----
    for (int r = 0; r < 8; ++r) {
        const int hl = w * 8 + r;
        const u16* p = Ih + ((size_t)b * 256 + h0 + hl) * 512 + lane * 8;
        shortx8 xv = *(const shortx8*)p;
        float I[8];
#pragma unroll
        for (int j = 0; j < 8; ++j) I[j] = bf2f((u16)xv[j]);
        float z = 0.f;
#pragma unroll
        for (int j = 0; j < 8; ++j) z += (I[j] - z) * 0.1f;
        float A = 0.43046721f, Bv = z;             // 0.9^8
#pragma unroll
        for (int d = 1; d < 64; d <<= 1) {
            const float Au = __shfl_up(A, d);
            const float Bu = __shfl_up(Bv, d);
            if (lane >= d) { Bv = fmaf(A, Bu, Bv); A *= Au; }
        }
        float v = __shfl_up(Bv, 1);
        if (lane == 0) v = 0.f;
        shortx8 sv;
#pragma unroll
        for (int j = 0; j < 8; ++j) {
            v += (I[j] - v) * 0.1f;
            sv[j] = (short)f2bf(sigmoid5(v));
        }
        *(shortx8*)&sbuf[hl * SROW + lane * 8] = sv;
    }
    __syncthreads();

    // ---- phase 2: dot via MFMA.  A[m=t][k=hl], B[k=hl][n=o] ----
    const int lg = lane >> 4, lr = lane & 15;
    shortx8 bw0, bw1;
#pragma unroll
    for (int j = 0; j < 8; ++j) {
        const int hA = h0 + lg * 8 + j;            // ks=0
        const int hB = hA + 32;                    // ks=1
        bw0[j] = (short)((lr < NO) ? f2bf(wr[hA * NO + lr]) : 0);
        bw1[j] = (short)((lr < NO) ? f2bf(wr[hB * NO + lr]) : 0);
    }
#pragma unroll
    for (int fi = 0; fi < 4; ++fi) {
        const int tf = w * 4 + fi;
        const int t  = tf * 16 + lr;
        floatx4 acc = (floatx4)0.f;
#pragma unroll
        for (int ks = 0; ks < 2; ++ks) {
            union { shortx8 s; u32 d[4]; } u;
#pragma unroll
            for (int q = 0; q < 4; ++q) {
                const int h1 = ks * 32 + lg * 8 + 2 * q;
                u.d[q] = (u32)sbuf[h1 * SROW + t] |
                         ((u32)sbuf[(h1 + 1) * SROW + t] << 16);
            }
            acc = __builtin_amdgcn_mfma_f32_16x16x32_bf16(
                u.s, (ks == 0) ? bw0 : bw1, acc, 0, 0, 0);
        }
        if (lr < NO) {
#pragma unroll
            for (int rr = 0; rr < 4; ++rr) {
                const int tt = tf * 16 + lg * 4 + rr;
                IoP[(((size_t)b * 512 + tt) * 4 + hg) * NO + lr] = acc[rr];
            }
        }
    }
}

// ---------- output LIF scan: sum 4 partials + segmented scan ----------
__global__ __launch_bounds__(256) void lif_out(
    const float* __restrict__ IoP,      // [128][512][4][10] f32
    float* __restrict__ out)
{
    __shared__ float Io[T_ * NO];       // 20KB
    __shared__ float vend[25][NO], vstart[25][NO], psum[25][NO];
    const int b = blockIdx.x, tid = threadIdx.x;

    for (int i = tid; i < T_ * NO; i += 256) {
        const int t = i / NO, o = i - t * NO;
        const float* q = IoP + ((size_t)b * 512 + t) * 40 + o;
        Io[i] = (q[0] + q[10]) + (q[20] + q[30]);
    }
    __syncthreads();

    const int seg = tid / NO, o = tid - seg * NO;
    if (tid < 250) {
        float v = 0.f;
#pragma unroll
        for (int j = 0; j < 20; ++j)
            v += (Io[(seg * 20 + j) * NO + o] - v) * 0.1f;
        vend[seg][o] = v;
    }
    __syncthreads();
    if (tid < NO) {
        float vs = 0.f;
#pragma unroll
        for (int sg = 0; sg < 25; ++sg) {
            vstart[sg][tid] = vs;
            vs = vend[sg][tid] + 0.12157665459f * vs;   // 0.9^20
        }
    }
    __syncthreads();
    if (tid < 250) {
        float v = vstart[seg][o], ps = 0.f;
#pragma unroll
        for (int j = 0; j < 20; ++j) {
            const int t = seg * 20 + j;
            v += (Io[t * NO + o] - v) * 0.1f;
            const float sv = sigmoid5(v);
            out[(size_t)b * (NO * T_) + (size_t)o * T_ + t] = sv;
            ps += sv;
        }
        psum[seg][o] = ps;
    }
    __syncthreads();
    if (tid < NO) {
        float tot = 0.f;
#pragma unroll
        for (int sg = 0; sg < 25; ++sg) tot += psum[sg][tid];
        out[(size_t)(B_ * NO) * T_ + b * NO + tid] = tot * (1.0f / T_);
    }
}

extern "C" void kernel_launch(void* const* d_in, const int* in_sizes, int n_in,
                              void* d_out, int out_size, void* d_ws, size_t ws_size,
                              hipStream_t stream) {
    (void)in_sizes; (void)n_in; (void)out_size; (void)ws_size;
    const float* spikes = (const float*)d_in[0];   // [128][784][500]
    const float* w_ih   = (const float*)d_in[1];   // [784][256]
    const float* w_ho   = (const float*)d_in[2];   // [256][10]
    float* out = (float*)d_out;

    float* wrelu = (float*)d_ws;                              // 10KB @0
    u16*   Bt    = (u16*)((char*)d_ws + 16384);               // 400KB
    u16*   Ih    = (u16*)((char*)d_ws + 524288);              // 33.55MB
    float* IoP   = (float*)((char*)d_ws + 524288 + 33554432); // 10.49MB

    convert_W  <<<NK * 32 + 1, 256, 0, stream>>>(w_ih, w_ho, Bt, wrelu);
    gemm_hidden<<<256, 1024, 0, stream>>>(spikes, Bt, Ih);
    scan_dot   <<<512, 512, 0, stream>>>(Ih, wrelu, IoP);
    lif_out    <<<B_, 256, 0, stream>>>(IoP, out);
}